// Round 11
// baseline (106.817 us; speedup 1.0000x reference)
//
#include <hip/hip_runtime.h>
#include <hip/hip_bf16.h>
#include <math.h>

#define TT 2048
#define HH 512   // hidden = NUM_HEADS*DIM_KEY
#define NH 8
#define DK 64
#define WIN 16
#define NC 33    // 2*WIN+1

// ===== DIAGNOSTIC ROUND: proj body x4, attn body x16 (idempotent reps) =====
// Purpose: single dispatches long enough (>43us) to crack the rocprof top-5
// (which is clogged by ~40us harness fillBuffer dispatches) and expose
// per-kernel dur/MfmaUtil/VALUBusy/Occupancy/FETCH/conflicts.
#define PROJ_REP 4
#define ATTN_REP 16

typedef __attribute__((ext_vector_type(8))) short bf16x8;
typedef __attribute__((ext_vector_type(4))) float f32x4;

__device__ inline ushort f2bf(float f) {   // RNE float -> bf16 bits
  uint u = __builtin_bit_cast(uint, f);
  return (ushort)((u + 0x7FFFu + ((u >> 16) & 1u)) >> 16);
}
__device__ inline ushort cvt1(float f) {   // compiler cast (v_cvt_pk capable)
  __hip_bfloat16 h = __float2bfloat16(f);
  return __builtin_bit_cast(ushort, h);
}

// ---------------- W fp32 -> bf16 pre-convert (weights only, 2 MB) ---------
__global__ __launch_bounds__(256) void cvt_w(
    const float* __restrict__ Wq, const float* __restrict__ Wk,
    ushort* __restrict__ Wqb, ushort* __restrict__ Wkb)
{
  const int id = blockIdx.x * 256 + threadIdx.x;   // 65536 tasks x 8 elems
  const float* src = (id < 32768) ? Wq : Wk;
  ushort* dst = (id < 32768) ? Wqb : Wkb;
  const int off = (id & 32767) * 8;
  float4 x = *(const float4*)(src + off);
  float4 y = *(const float4*)(src + off + 4);
  union { ushort s[8]; uint4 v; } pk;
  pk.s[0]=cvt1(x.x); pk.s[1]=cvt1(x.y); pk.s[2]=cvt1(x.z); pk.s[3]=cvt1(x.w);
  pk.s[4]=cvt1(y.x); pk.s[5]=cvt1(y.y); pk.s[6]=cvt1(y.z); pk.s[7]=cvt1(y.w);
  *(uint4*)(dst + off) = pk.v;
}

// ---------------- projection GEMM (bf16 MFMA), R10 structure, x4 reps -----
#define PBM 64
#define PBN 128
#define PBK 64

__global__ __launch_bounds__(256, 4) void proj_mfma(
    const float* __restrict__ Aq, const float* __restrict__ Ak,
    const ushort* __restrict__ Wqb, const ushort* __restrict__ Wkb,
    const float* __restrict__ bq, const float* __restrict__ bk,
    ushort* __restrict__ Qp, ushort* __restrict__ Kp)
{
  __shared__ ushort As[PBM * PBK];   // 8 KB
  __shared__ ushort Ws[PBN * PBK];   // 16 KB

  const int z = blockIdx.z;
  const float*  A    = z ? Ak  : Aq;
  const ushort* Wb   = z ? Wkb : Wqb;
  const float*  bias = z ? bk  : bq;
  ushort*       C    = z ? Kp  : Qp;

  const int m0 = blockIdx.x * PBM;
  const int n0 = blockIdx.y * PBN;
  const int t  = threadIdx.x;
  const int l  = t & 63;
  const int w  = t >> 6;
  const int wr = (w >> 1) * 32;   // wave row offset (2 wave-rows of 32)
  const int wc = (w & 1) * 64;    // wave col offset (2 wave-cols of 64)
  const int lr = l & 15;
  const int hi = l >> 4;
  const int swz = lr & 7;         // fragment-row swizzle key

  for (int rep = 0; rep < PROJ_REP; ++rep) {
    f32x4 acc[2][4] = {};

    for (int k0 = 0; k0 < HH; k0 += PBK) {
      // ---- W: 128x64 = 1024 granules, 4 global_load_lds (swizzled src) ----
#pragma unroll
      for (int p = 0; p < 4; ++p) {
        const int u = p * 256 + t;
        const int r = u >> 3;
        const int g = (u & 7) ^ (r & 7);
        __builtin_amdgcn_global_load_lds(
            (const __attribute__((address_space(1))) uint*)
                (Wb + (size_t)(n0 + r) * HH + k0 + g * 8),
            (__attribute__((address_space(3))) uint*)(Ws + p * 2048 + w * 512),
            16, 0, 0);
      }
      // ---- A: 64x64 = 512 granules, 2/thread, fp32->bf16, linear dest ----
#pragma unroll
      for (int p = 0; p < 2; ++p) {
        const int u = p * 256 + t;
        const int r = u >> 3;
        const int g = (u & 7) ^ (r & 7);
        const float* gp = A + (size_t)(m0 + r) * HH + k0 + g * 8;
        float4 x = ((const float4*)gp)[0], y = ((const float4*)gp)[1];
        union { ushort s[8]; uint4 v; } pk;
        pk.s[0]=cvt1(x.x); pk.s[1]=cvt1(x.y); pk.s[2]=cvt1(x.z); pk.s[3]=cvt1(x.w);
        pk.s[4]=cvt1(y.x); pk.s[5]=cvt1(y.y); pk.s[6]=cvt1(y.z); pk.s[7]=cvt1(y.w);
        *(uint4*)&As[u * 8] = pk.v;
      }
      __syncthreads();

#pragma unroll
      for (int kk = 0; kk < PBK; kk += 32) {
        const int gq = (kk >> 3) + hi;        // needed column granule
        bf16x8 af[2], bf[4];
#pragma unroll
        for (int m = 0; m < 2; ++m)
          af[m] = *(const bf16x8*)&As[(wr + m * 16 + lr) * PBK + ((gq ^ swz) * 8)];
#pragma unroll
        for (int n = 0; n < 4; ++n)
          bf[n] = *(const bf16x8*)&Ws[(wc + n * 16 + lr) * PBK + ((gq ^ swz) * 8)];
#pragma unroll
        for (int m = 0; m < 2; ++m)
#pragma unroll
          for (int n = 0; n < 4; ++n)
            acc[m][n] = __builtin_amdgcn_mfma_f32_16x16x32_bf16(af[m], bf[n], acc[m][n], 0, 0, 0);
      }
      __syncthreads();
    }

    // ---- epilogue: D row=(l>>4)*4+q, col=l&15 ----
#pragma unroll
    for (int n = 0; n < 4; ++n) {
      const int col = n0 + wc + n * 16 + lr;
      const float bc = bias[col];
#pragma unroll
      for (int m = 0; m < 2; ++m) {
        const int rbase = m0 + wr + m * 16 + hi * 4;
#pragma unroll
        for (int q = 0; q < 4; ++q)
          C[(size_t)(rbase + q) * HH + col] = f2bf(acc[m][n][q] + bc);
      }
    }
    asm volatile("" ::: "memory");   // block cross-rep CSE / dead-store elim
    __syncthreads();
  }
}

// ---------------- MFMA windowed attention + softmax + gather, x16 reps ----
__global__ __launch_bounds__(256) void attn_mfma(
    const ushort* __restrict__ Q, const ushort* __restrict__ Kp,
    float* __restrict__ out)
{
  const int gw = blockIdx.x * 4 + (threadIdx.x >> 6);   // 0..4095
  const int h = gw & 7;
  const int tile = gw >> 3;          // 0..511
  const int b = tile >> 7;           // 128 row-tiles per batch
  const int i0 = (tile & 127) * 16;
  const int l = threadIdx.x & 63;
  const int lo = l & 15;             // fragment row/col lane index
  const int hi = l >> 4;             // k-slice / acc row-group

  int jb = i0 - WIN;                 // start(i0) = clip(i0-16,0,T-33)
  if (jb < 0) jb = 0;
  if (jb > TT - NC) jb = TT - NC;

  for (int rep = 0; rep < ATTN_REP; ++rep) {
    const size_t qbase = ((size_t)(b * TT + i0 + lo)) * HH + h * DK + hi * 8;
    bf16x8 aq0 = *(const bf16x8*)(Q + qbase);
    bf16x8 aq1 = *(const bf16x8*)(Q + qbase + 32);

    f32x4 acc[3] = {};
#pragma unroll
    for (int a = 0; a < 3; ++a) {
      int j = jb + a * 16 + lo;
      if (j > TT - 1) j = TT - 1;      // clamped loads get masked below
      const size_t kbase = ((size_t)(b * TT + j)) * HH + h * DK + hi * 8;
      bf16x8 bk0 = *(const bf16x8*)(Kp + kbase);
      bf16x8 bk1 = *(const bf16x8*)(Kp + kbase + 32);
      acc[a] = __builtin_amdgcn_mfma_f32_16x16x32_bf16(aq0, bk0, acc[a], 0, 0, 0);
      acc[a] = __builtin_amdgcn_mfma_f32_16x16x32_bf16(aq1, bk1, acc[a], 0, 0, 0);
    }

    float e[3][4];
    float inv[4];
#pragma unroll
    for (int q = 0; q < 4; ++q) {
      const int i = i0 + hi * 4 + q;
      const int j0 = jb + lo, j1 = j0 + 16, j2 = j0 + 32;
      float s0 = (j0 >= i - WIN && j0 <= i + WIN && j0 < TT) ? acc[0][q] * 0.125f : -INFINITY;
      float s1 = (j1 >= i - WIN && j1 <= i + WIN && j1 < TT) ? acc[1][q] * 0.125f : -INFINITY;
      float s2 = (j2 >= i - WIN && j2 <= i + WIN && j2 < TT) ? acc[2][q] * 0.125f : -INFINITY;
      float m = fmaxf(fmaxf(s0, s1), s2);
#pragma unroll
      for (int off = 8; off; off >>= 1) m = fmaxf(m, __shfl_xor(m, off));
      const float e0 = __expf(s0 - m);
      const float e1 = __expf(s1 - m);
      const float e2 = __expf(s2 - m);
      e[0][q] = e0; e[1][q] = e1; e[2][q] = e2;
      float sum = e0 + e1 + e2;
#pragma unroll
      for (int off = 8; off; off >>= 1) sum += __shfl_xor(sum, off);
      inv[q] = 1.0f / sum;
    }

    const size_t obase = ((size_t)(b * NH + h)) * TT * NC;
#pragma unroll
    for (int q = 0; q < 4; ++q) {
      const int i = i0 + hi * 4 + q;
      int st = i - WIN;
      if (st < 0) st = 0;
      if (st > TT - NC) st = TT - NC;
#pragma unroll
      for (int a = 0; a < 3; ++a) {
        const int c = jb + a * 16 + lo - st;
        if (c >= 0 && c < NC)
          out[obase + (size_t)i * NC + c] = e[a][q] * inv[q];
      }
    }
    asm volatile("" ::: "memory");   // block cross-rep CSE / dead-store elim
  }
}

extern "C" void kernel_launch(void* const* d_in, const int* in_sizes, int n_in,
                              void* d_out, int out_size, void* d_ws, size_t ws_size,
                              hipStream_t stream)
{
  const float* query = (const float*)d_in[0];
  const float* key   = (const float*)d_in[1];
  const float* Wq    = (const float*)d_in[2];
  const float* bq    = (const float*)d_in[3];
  const float* Wk    = (const float*)d_in[4];
  const float* bk    = (const float*)d_in[5];
  float* out = (float*)d_out;

  const int B = 4, M = B * TT;      // 8192 rows
  ushort* Wqb = (ushort*)d_ws;                  // 512x512 bf16
  ushort* Wkb = Wqb + (size_t)HH * HH;
  ushort* Qp  = Wkb + (size_t)HH * HH;          // [M,512] bf16 projected
  ushort* Kp  = Qp + (size_t)M * HH;

  cvt_w<<<dim3(256), 256, 0, stream>>>(Wq, Wk, Wqb, Wkb);
  proj_mfma<<<dim3(M / PBM, HH / PBN, 2), 256, 0, stream>>>(
      query, key, Wqb, Wkb, bq, bk, Qp, Kp);
  attn_mfma<<<dim3((M / 16) * NH / 4), 256, 0, stream>>>(Qp, Kp, out);
}

// Round 12
// 37.174 us; speedup vs baseline: 2.8735x; 2.8735x over previous
//
#include <hip/hip_runtime.h>
#include <hip/hip_bf16.h>
#include <math.h>

#define TT 2048
#define HH 512   // hidden = NUM_HEADS*DIM_KEY
#define NH 8
#define DK 64
#define WIN 16
#define NC 33    // 2*WIN+1

typedef __attribute__((ext_vector_type(8))) short bf16x8;
typedef __attribute__((ext_vector_type(4))) float f32x4;

__device__ inline ushort f2bf(float f) {   // RNE float -> bf16 bits
  uint u = __builtin_bit_cast(uint, f);
  return (ushort)((u + 0x7FFFu + ((u >> 16) & 1u)) >> 16);
}
__device__ inline ushort cvt1(float f) {   // compiler cast (v_cvt_pk capable)
  __hip_bfloat16 h = __float2bfloat16(f);
  return __builtin_bit_cast(ushort, h);
}

// ---------------- W fp32 -> bf16 pre-convert (weights only, 2 MB) ---------
__global__ __launch_bounds__(256) void cvt_w(
    const float* __restrict__ Wq, const float* __restrict__ Wk,
    ushort* __restrict__ Wqb, ushort* __restrict__ Wkb)
{
  const int id = blockIdx.x * 256 + threadIdx.x;   // 65536 tasks x 8 elems
  const float* src = (id < 32768) ? Wq : Wk;
  ushort* dst = (id < 32768) ? Wqb : Wkb;
  const int off = (id & 32767) * 8;
  float4 x = *(const float4*)(src + off);
  float4 y = *(const float4*)(src + off + 4);
  union { ushort s[8]; uint4 v; } pk;
  pk.s[0]=cvt1(x.x); pk.s[1]=cvt1(x.y); pk.s[2]=cvt1(x.z); pk.s[3]=cvt1(x.w);
  pk.s[4]=cvt1(y.x); pk.s[5]=cvt1(y.y); pk.s[6]=cvt1(y.z); pk.s[7]=cvt1(y.w);
  *(uint4*)(dst + off) = pk.v;
}

// ---------------- projection GEMM (bf16 MFMA): C = A @ W^T + b, bf16 out --
// T4 counted-vmcnt pipeline (R11 counters: latency-bound staging; R9's
// __syncthreads drained vmcnt(0) at every barrier = m218's drain0 ≈ no pipe).
// 3-buffer W (global_load_lds, prefetch 2 ahead), 2-buffer A (reg-staged,
// 1 ahead). Per iter t: issue A(t+1), issue W(t+2)->Wbuf[(t+2)%3], MFMA on
// buf(t), s_waitcnt vmcnt(4)  [drains W(t+1)+A(t+1); W(t+2)'s 4 loads stay
// in flight ACROSS the raw s_barrier], cvt+ds_write A(t+1), lgkmcnt(0),
// s_barrier. Buffer safety: Wbuf[(t+2)%3] was last read at iter t-1 (barrier
// passed); Abuf[(t+1)&1] last read at t-1. One barrier per iter.
#define PBM 64
#define PBN 128
#define PBK 64
#define NKI 8    // K iterations = HH/PBK

#define ISSUE_W(kt, buf) \
  _Pragma("unroll") for (int p = 0; p < 4; ++p) { \
    const int u = p * 256 + t; const int r = u >> 3; \
    const int g = (u & 7) ^ (r & 7); \
    __builtin_amdgcn_global_load_lds( \
        (const __attribute__((address_space(1))) uint*) \
            (Wb + (size_t)(n0 + r) * HH + (kt) * PBK + g * 8), \
        (__attribute__((address_space(3))) uint*)(&Ws[buf][p * 2048 + w * 512]), \
        16, 0, 0); \
  }

#define ISSUE_A(kt) \
  _Pragma("unroll") for (int p = 0; p < 2; ++p) { \
    const int u = p * 256 + t; const int r = u >> 3; \
    const int g = (u & 7) ^ (r & 7); \
    const float* gp = A + (size_t)(m0 + r) * HH + (kt) * PBK + g * 8; \
    ax[p] = ((const float4*)gp)[0]; ay[p] = ((const float4*)gp)[1]; \
  }

#define WRITE_A(buf) \
  _Pragma("unroll") for (int p = 0; p < 2; ++p) { \
    union { ushort s[8]; uint4 v; } pk; \
    pk.s[0]=cvt1(ax[p].x); pk.s[1]=cvt1(ax[p].y); pk.s[2]=cvt1(ax[p].z); pk.s[3]=cvt1(ax[p].w); \
    pk.s[4]=cvt1(ay[p].x); pk.s[5]=cvt1(ay[p].y); pk.s[6]=cvt1(ay[p].z); pk.s[7]=cvt1(ay[p].w); \
    *(uint4*)&As[buf][(p * 256 + t) * 8] = pk.v; \
  }

#define COMPUTE(wbuf, abuf) \
  _Pragma("unroll") for (int kk = 0; kk < PBK; kk += 32) { \
    const int gq = (kk >> 3) + hi; \
    bf16x8 af[2], bfv[4]; \
    _Pragma("unroll") for (int m = 0; m < 2; ++m) \
      af[m] = *(const bf16x8*)&As[abuf][(wr + m * 16 + lr) * PBK + ((gq ^ swz) * 8)]; \
    _Pragma("unroll") for (int n = 0; n < 4; ++n) \
      bfv[n] = *(const bf16x8*)&Ws[wbuf][(wc + n * 16 + lr) * PBK + ((gq ^ swz) * 8)]; \
    _Pragma("unroll") for (int m = 0; m < 2; ++m) \
      _Pragma("unroll") for (int n = 0; n < 4; ++n) \
        acc[m][n] = __builtin_amdgcn_mfma_f32_16x16x32_bf16(af[m], bfv[n], acc[m][n], 0, 0, 0); \
  }

__global__ __launch_bounds__(256) void proj_mfma(
    const float* __restrict__ Aq, const float* __restrict__ Ak,
    const ushort* __restrict__ Wqb, const ushort* __restrict__ Wkb,
    const float* __restrict__ bq, const float* __restrict__ bk,
    ushort* __restrict__ Qp, ushort* __restrict__ Kp)
{
  __shared__ ushort As[2][PBM * PBK];   // 2 x 8 KB
  __shared__ ushort Ws[3][PBN * PBK];   // 3 x 16 KB  (64 KB total)

  const int z = blockIdx.z;
  const float*  A    = z ? Ak  : Aq;
  const ushort* Wb   = z ? Wkb : Wqb;
  const float*  bias = z ? bk  : bq;
  ushort*       C    = z ? Kp  : Qp;

  const int m0 = blockIdx.x * PBM;
  const int n0 = blockIdx.y * PBN;
  const int t  = threadIdx.x;
  const int l  = t & 63;
  const int w  = t >> 6;
  const int wr = (w >> 1) * 32;   // wave row offset
  const int wc = (w & 1) * 64;    // wave col offset
  const int lr = l & 15;
  const int hi = l >> 4;
  const int swz = lr & 7;         // fragment-row swizzle key

  f32x4 acc[2][4] = {};
  float4 ax[2], ay[2];

  // ---- prologue: A(0)+W(0) needed now; W(1) left in flight ----
  ISSUE_A(0);
  ISSUE_W(0, 0);
  ISSUE_W(1, 1);
  asm volatile("s_waitcnt vmcnt(4)" ::: "memory");   // A(0),W(0) landed
  WRITE_A(0);
  asm volatile("s_waitcnt lgkmcnt(0)" ::: "memory");
  __builtin_amdgcn_s_barrier();
  __builtin_amdgcn_sched_barrier(0);

#pragma unroll
  for (int tt = 0; tt < NKI; ++tt) {
    if (tt + 1 < NKI) { ISSUE_A(tt + 1); }
    if (tt + 2 < NKI) { ISSUE_W(tt + 2, (tt + 2) % 3); }
    __builtin_amdgcn_sched_barrier(0);   // pin issues before compute
    COMPUTE(tt % 3, tt & 1);
    if (tt + 1 < NKI) {
      if (tt + 2 < NKI) {
        asm volatile("s_waitcnt vmcnt(4)" ::: "memory");  // W(t+1),A(t+1) in; W(t+2) stays out
      } else {
        asm volatile("s_waitcnt vmcnt(0)" ::: "memory");  // tail: drain all
      }
      WRITE_A((tt + 1) & 1);
      asm volatile("s_waitcnt lgkmcnt(0)" ::: "memory");
      __builtin_amdgcn_s_barrier();
      __builtin_amdgcn_sched_barrier(0);
    }
  }

  // ---- epilogue: D row=(l>>4)*4+q, col=l&15 (rounds 3-11 verified) ----
#pragma unroll
  for (int n = 0; n < 4; ++n) {
    const int col = n0 + wc + n * 16 + lr;
    const float bc = bias[col];
#pragma unroll
    for (int m = 0; m < 2; ++m) {
      const int rbase = m0 + wr + m * 16 + hi * 4;
#pragma unroll
      for (int q = 0; q < 4; ++q)
        C[(size_t)(rbase + q) * HH + col] = f2bf(acc[m][n][q] + bc);
    }
  }
}

// ---------------- MFMA windowed attention + softmax + gather --------------
// One wave per (16-row tile, head); S[16][48] via 6 MFMAs, fragments direct
// from global; in-register softmax; scatter to gathered layout.
__global__ __launch_bounds__(256) void attn_mfma(
    const ushort* __restrict__ Q, const ushort* __restrict__ Kp,
    float* __restrict__ out)
{
  const int gw = blockIdx.x * 4 + (threadIdx.x >> 6);   // 0..4095
  const int h = gw & 7;
  const int tile = gw >> 3;          // 0..511
  const int b = tile >> 7;           // 128 row-tiles per batch
  const int i0 = (tile & 127) * 16;
  const int l = threadIdx.x & 63;
  const int lo = l & 15;             // fragment row/col lane index
  const int hi = l >> 4;             // k-slice / acc row-group

  int jb = i0 - WIN;                 // start(i0) = clip(i0-16,0,T-33)
  if (jb < 0) jb = 0;
  if (jb > TT - NC) jb = TT - NC;

  const size_t qbase = ((size_t)(b * TT + i0 + lo)) * HH + h * DK + hi * 8;
  bf16x8 aq0 = *(const bf16x8*)(Q + qbase);
  bf16x8 aq1 = *(const bf16x8*)(Q + qbase + 32);

  f32x4 acc[3] = {};
#pragma unroll
  for (int a = 0; a < 3; ++a) {
    int j = jb + a * 16 + lo;
    if (j > TT - 1) j = TT - 1;      // clamped loads get masked below
    const size_t kbase = ((size_t)(b * TT + j)) * HH + h * DK + hi * 8;
    bf16x8 bk0 = *(const bf16x8*)(Kp + kbase);
    bf16x8 bk1 = *(const bf16x8*)(Kp + kbase + 32);
    acc[a] = __builtin_amdgcn_mfma_f32_16x16x32_bf16(aq0, bk0, acc[a], 0, 0, 0);
    acc[a] = __builtin_amdgcn_mfma_f32_16x16x32_bf16(aq1, bk1, acc[a], 0, 0, 0);
  }

  float e[3][4];
  float inv[4];
#pragma unroll
  for (int q = 0; q < 4; ++q) {
    const int i = i0 + hi * 4 + q;
    const int j0 = jb + lo, j1 = j0 + 16, j2 = j0 + 32;
    float s0 = (j0 >= i - WIN && j0 <= i + WIN && j0 < TT) ? acc[0][q] * 0.125f : -INFINITY;
    float s1 = (j1 >= i - WIN && j1 <= i + WIN && j1 < TT) ? acc[1][q] * 0.125f : -INFINITY;
    float s2 = (j2 >= i - WIN && j2 <= i + WIN && j2 < TT) ? acc[2][q] * 0.125f : -INFINITY;
    float m = fmaxf(fmaxf(s0, s1), s2);
#pragma unroll
    for (int off = 8; off; off >>= 1) m = fmaxf(m, __shfl_xor(m, off));
    const float e0 = __expf(s0 - m);
    const float e1 = __expf(s1 - m);
    const float e2 = __expf(s2 - m);
    e[0][q] = e0; e[1][q] = e1; e[2][q] = e2;
    float sum = e0 + e1 + e2;
#pragma unroll
    for (int off = 8; off; off >>= 1) sum += __shfl_xor(sum, off);
    inv[q] = 1.0f / sum;
  }

  const size_t obase = ((size_t)(b * NH + h)) * TT * NC;
#pragma unroll
  for (int q = 0; q < 4; ++q) {
    const int i = i0 + hi * 4 + q;
    int st = i - WIN;
    if (st < 0) st = 0;
    if (st > TT - NC) st = TT - NC;
#pragma unroll
    for (int a = 0; a < 3; ++a) {
      const int c = jb + a * 16 + lo - st;
      if (c >= 0 && c < NC)
        out[obase + (size_t)i * NC + c] = e[a][q] * inv[q];
    }
  }
}

extern "C" void kernel_launch(void* const* d_in, const int* in_sizes, int n_in,
                              void* d_out, int out_size, void* d_ws, size_t ws_size,
                              hipStream_t stream)
{
  const float* query = (const float*)d_in[0];
  const float* key   = (const float*)d_in[1];
  const float* Wq    = (const float*)d_in[2];
  const float* bq    = (const float*)d_in[3];
  const float* Wk    = (const float*)d_in[4];
  const float* bk    = (const float*)d_in[5];
  float* out = (float*)d_out;

  const int B = 4, M = B * TT;      // 8192 rows
  ushort* Wqb = (ushort*)d_ws;                  // 512x512 bf16
  ushort* Wkb = Wqb + (size_t)HH * HH;
  ushort* Qp  = Wkb + (size_t)HH * HH;          // [M,512] bf16 projected
  ushort* Kp  = Qp + (size_t)M * HH;

  cvt_w<<<dim3(256), 256, 0, stream>>>(Wq, Wk, Wqb, Wkb);
  proj_mfma<<<dim3(M / PBM, HH / PBN, 2), 256, 0, stream>>>(
      query, key, Wqb, Wkb, bq, bk, Qp, Kp);
  attn_mfma<<<dim3((M / 16) * NH / 4), 256, 0, stream>>>(Qp, Kp, out);
}

// Round 13
// 37.118 us; speedup vs baseline: 2.8778x; 1.0015x over previous
//
#include <hip/hip_runtime.h>
#include <hip/hip_bf16.h>
#include <math.h>

#define TT 2048
#define HH 512   // hidden = NUM_HEADS*DIM_KEY
#define NH 8
#define DK 64
#define WIN 16
#define NC 33    // 2*WIN+1

typedef __attribute__((ext_vector_type(8))) short bf16x8;
typedef __attribute__((ext_vector_type(4))) float f32x4;

__device__ inline ushort f2bf(float f) {   // RNE float -> bf16 bits
  uint u = __builtin_bit_cast(uint, f);
  return (ushort)((u + 0x7FFFu + ((u >> 16) & 1u)) >> 16);
}
__device__ inline ushort cvt1(float f) {   // compiler cast (v_cvt_pk capable)
  __hip_bfloat16 h = __float2bfloat16(f);
  return __builtin_bit_cast(ushort, h);
}

// ---------------- projection GEMM (bf16 MFMA): C = A @ W^T + b, bf16 out --
// TWO-DISPATCH ROUND: cvt_w folded in — W staged fp32->bf16 in-kernel
// (reg-staged, same as A). R10 body otherwise (2-barrier loop, 16B-granule
// XOR swizzle: swizzled source granule, linear dest, swizzled read).
// R11 counters said proj is latency-bound (MfmaUtil 19, VALUBusy 16, Occ 32)
// and R8-R12 proved structure variants are all equal — so the extra cvt
// VALU should be nearly free; the win is one fewer dispatch (~4-6 us gap).
#define PBM 64
#define PBN 128
#define PBK 64

__global__ __launch_bounds__(256, 4) void proj_mfma(
    const float* __restrict__ Aq, const float* __restrict__ Ak,
    const float* __restrict__ Wqf, const float* __restrict__ Wkf,
    const float* __restrict__ bq, const float* __restrict__ bk,
    ushort* __restrict__ Qp, ushort* __restrict__ Kp)
{
  __shared__ ushort As[PBM * PBK];   // 8 KB
  __shared__ ushort Ws[PBN * PBK];   // 16 KB

  const int z = blockIdx.z;
  const float*  A    = z ? Ak  : Aq;
  const float*  Wf   = z ? Wkf : Wqf;
  const float*  bias = z ? bk  : bq;
  ushort*       C    = z ? Kp  : Qp;

  const int m0 = blockIdx.x * PBM;
  const int n0 = blockIdx.y * PBN;
  const int t  = threadIdx.x;
  const int l  = t & 63;
  const int w  = t >> 6;
  const int wr = (w >> 1) * 32;   // wave row offset (2 wave-rows of 32)
  const int wc = (w & 1) * 64;    // wave col offset (2 wave-cols of 64)
  const int lr = l & 15;
  const int hi = l >> 4;
  const int swz = lr & 7;         // fragment-row swizzle key

  f32x4 acc[2][4] = {};

  for (int k0 = 0; k0 < HH; k0 += PBK) {
    // ---- issue ALL staging loads first (12 x dwordx4), then cvt+write ----
    float4 wx[4], wy[4], ax[2], ay[2];
#pragma unroll
    for (int p = 0; p < 4; ++p) {          // W: 1024 granules, 4/thread
      const int u = p * 256 + t;
      const int r = u >> 3;
      const int g = (u & 7) ^ (r & 7);
      const float* gp = Wf + (size_t)(n0 + r) * HH + k0 + g * 8;
      wx[p] = ((const float4*)gp)[0];
      wy[p] = ((const float4*)gp)[1];
    }
#pragma unroll
    for (int p = 0; p < 2; ++p) {          // A: 512 granules, 2/thread
      const int u = p * 256 + t;
      const int r = u >> 3;
      const int g = (u & 7) ^ (r & 7);
      const float* gp = A + (size_t)(m0 + r) * HH + k0 + g * 8;
      ax[p] = ((const float4*)gp)[0];
      ay[p] = ((const float4*)gp)[1];
    }
#pragma unroll
    for (int p = 0; p < 4; ++p) {
      union { ushort s[8]; uint4 v; } pk;
      pk.s[0]=cvt1(wx[p].x); pk.s[1]=cvt1(wx[p].y); pk.s[2]=cvt1(wx[p].z); pk.s[3]=cvt1(wx[p].w);
      pk.s[4]=cvt1(wy[p].x); pk.s[5]=cvt1(wy[p].y); pk.s[6]=cvt1(wy[p].z); pk.s[7]=cvt1(wy[p].w);
      *(uint4*)&Ws[(p * 256 + t) * 8] = pk.v;
    }
#pragma unroll
    for (int p = 0; p < 2; ++p) {
      union { ushort s[8]; uint4 v; } pk;
      pk.s[0]=cvt1(ax[p].x); pk.s[1]=cvt1(ax[p].y); pk.s[2]=cvt1(ax[p].z); pk.s[3]=cvt1(ax[p].w);
      pk.s[4]=cvt1(ay[p].x); pk.s[5]=cvt1(ay[p].y); pk.s[6]=cvt1(ay[p].z); pk.s[7]=cvt1(ay[p].w);
      *(uint4*)&As[(p * 256 + t) * 8] = pk.v;
    }
    __syncthreads();

#pragma unroll
    for (int kk = 0; kk < PBK; kk += 32) {
      const int gq = (kk >> 3) + hi;        // needed column granule
      bf16x8 af[2], bf[4];
#pragma unroll
      for (int m = 0; m < 2; ++m)
        af[m] = *(const bf16x8*)&As[(wr + m * 16 + lr) * PBK + ((gq ^ swz) * 8)];
#pragma unroll
      for (int n = 0; n < 4; ++n)
        bf[n] = *(const bf16x8*)&Ws[(wc + n * 16 + lr) * PBK + ((gq ^ swz) * 8)];
#pragma unroll
      for (int m = 0; m < 2; ++m)
#pragma unroll
        for (int n = 0; n < 4; ++n)
          acc[m][n] = __builtin_amdgcn_mfma_f32_16x16x32_bf16(af[m], bf[n], acc[m][n], 0, 0, 0);
    }
    __syncthreads();
  }

  // ---- epilogue: D row=(l>>4)*4+q, col=l&15 (rounds 3-12 verified) ----
#pragma unroll
  for (int n = 0; n < 4; ++n) {
    const int col = n0 + wc + n * 16 + lr;
    const float bc = bias[col];
#pragma unroll
    for (int m = 0; m < 2; ++m) {
      const int rbase = m0 + wr + m * 16 + hi * 4;
#pragma unroll
      for (int q = 0; q < 4; ++q)
        C[(size_t)(rbase + q) * HH + col] = f2bf(acc[m][n][q] + bc);
    }
  }
}

// ---------------- MFMA windowed attention + softmax + gather --------------
// One wave per (16-row tile, head); S[16][48] via 6 MFMAs, fragments direct
// from global; in-register softmax; scatter to gathered layout.
__global__ __launch_bounds__(256) void attn_mfma(
    const ushort* __restrict__ Q, const ushort* __restrict__ Kp,
    float* __restrict__ out)
{
  const int gw = blockIdx.x * 4 + (threadIdx.x >> 6);   // 0..4095
  const int h = gw & 7;
  const int tile = gw >> 3;          // 0..511
  const int b = tile >> 7;           // 128 row-tiles per batch
  const int i0 = (tile & 127) * 16;
  const int l = threadIdx.x & 63;
  const int lo = l & 15;             // fragment row/col lane index
  const int hi = l >> 4;             // k-slice / acc row-group

  int jb = i0 - WIN;                 // start(i0) = clip(i0-16,0,T-33)
  if (jb < 0) jb = 0;
  if (jb > TT - NC) jb = TT - NC;

  const size_t qbase = ((size_t)(b * TT + i0 + lo)) * HH + h * DK + hi * 8;
  bf16x8 aq0 = *(const bf16x8*)(Q + qbase);
  bf16x8 aq1 = *(const bf16x8*)(Q + qbase + 32);

  f32x4 acc[3] = {};
#pragma unroll
  for (int a = 0; a < 3; ++a) {
    int j = jb + a * 16 + lo;
    if (j > TT - 1) j = TT - 1;      // clamped loads get masked below
    const size_t kbase = ((size_t)(b * TT + j)) * HH + h * DK + hi * 8;
    bf16x8 bk0 = *(const bf16x8*)(Kp + kbase);
    bf16x8 bk1 = *(const bf16x8*)(Kp + kbase + 32);
    acc[a] = __builtin_amdgcn_mfma_f32_16x16x32_bf16(aq0, bk0, acc[a], 0, 0, 0);
    acc[a] = __builtin_amdgcn_mfma_f32_16x16x32_bf16(aq1, bk1, acc[a], 0, 0, 0);
  }

  float e[3][4];
  float inv[4];
#pragma unroll
  for (int q = 0; q < 4; ++q) {
    const int i = i0 + hi * 4 + q;
    const int j0 = jb + lo, j1 = j0 + 16, j2 = j0 + 32;
    float s0 = (j0 >= i - WIN && j0 <= i + WIN && j0 < TT) ? acc[0][q] * 0.125f : -INFINITY;
    float s1 = (j1 >= i - WIN && j1 <= i + WIN && j1 < TT) ? acc[1][q] * 0.125f : -INFINITY;
    float s2 = (j2 >= i - WIN && j2 <= i + WIN && j2 < TT) ? acc[2][q] * 0.125f : -INFINITY;
    float m = fmaxf(fmaxf(s0, s1), s2);
#pragma unroll
    for (int off = 8; off; off >>= 1) m = fmaxf(m, __shfl_xor(m, off));
    const float e0 = __expf(s0 - m);
    const float e1 = __expf(s1 - m);
    const float e2 = __expf(s2 - m);
    e[0][q] = e0; e[1][q] = e1; e[2][q] = e2;
    float sum = e0 + e1 + e2;
#pragma unroll
    for (int off = 8; off; off >>= 1) sum += __shfl_xor(sum, off);
    inv[q] = 1.0f / sum;
  }

  const size_t obase = ((size_t)(b * NH + h)) * TT * NC;
#pragma unroll
  for (int q = 0; q < 4; ++q) {
    const int i = i0 + hi * 4 + q;
    int st = i - WIN;
    if (st < 0) st = 0;
    if (st > TT - NC) st = TT - NC;
#pragma unroll
    for (int a = 0; a < 3; ++a) {
      const int c = jb + a * 16 + lo - st;
      if (c >= 0 && c < NC)
        out[obase + (size_t)i * NC + c] = e[a][q] * inv[q];
    }
  }
}

extern "C" void kernel_launch(void* const* d_in, const int* in_sizes, int n_in,
                              void* d_out, int out_size, void* d_ws, size_t ws_size,
                              hipStream_t stream)
{
  const float* query = (const float*)d_in[0];
  const float* key   = (const float*)d_in[1];
  const float* Wq    = (const float*)d_in[2];
  const float* bq    = (const float*)d_in[3];
  const float* Wk    = (const float*)d_in[4];
  const float* bk    = (const float*)d_in[5];
  float* out = (float*)d_out;

  const int B = 4, M = B * TT;      // 8192 rows
  ushort* Qp  = (ushort*)d_ws;                  // [M,512] bf16 projected
  ushort* Kp  = Qp + (size_t)M * HH;

  proj_mfma<<<dim3(M / PBM, HH / PBN, 2), 256, 0, stream>>>(
      query, key, Wq, Wk, bq, bk, Qp, Kp);
  attn_mfma<<<dim3((M / 16) * NH / 4), 256, 0, stream>>>(Qp, Kp, out);
}